// Round 2
// baseline (954.514 us; speedup 1.0000x reference)
//
#include <hip/hip_runtime.h>

#define BATCH 16384
#define NNODE 23
#define NF    16
#define HID   128
#define MROWS (BATCH * NNODE)   // 376832
#define MBLK  (MROWS / 16)      // 23552 (exact)

typedef unsigned short u16;
typedef unsigned int   u32;
typedef __attribute__((ext_vector_type(8))) short s16x8;  // 8 bf16 (guide-verified frag type)
typedef __attribute__((ext_vector_type(4))) float f32x4;

__device__ __forceinline__ float bf2f(u16 v) {
    union { u32 i; float f; } u; u.i = ((u32)v) << 16; return u.f;
}
__device__ __forceinline__ u16 f2bf(float f) {
    union { float f; u32 i; } u; u.f = f;
    return (u16)((u.i + 0x7FFFu + ((u.i >> 16) & 1u)) >> 16);  // RNE
}
__device__ __forceinline__ float sigm(float x) { return 1.0f / (1.0f + __expf(-x)); }
__device__ __forceinline__ float tanh_fast(float x) {
    float e = __expf(2.0f * x);          // inf/0 saturate -> +/-1, safe
    return 1.0f - 2.0f / (e + 1.0f);
}

// flag-branched scalar load / store (f32 is wave-uniform)
__device__ __forceinline__ float lds1(const void* base, size_t i, int f32) {
    return f32 ? ((const float*)base)[i] : bf2f(((const u16*)base)[i]);
}
__device__ __forceinline__ void st1(void* base, size_t i, int f32, float v) {
    if (f32) ((float*)base)[i] = v;
    else     ((u16*)base)[i]   = f2bf(v);
}
// 8-element MFMA fragment load (elem_off multiple of 8 -> aligned both modes)
__device__ __forceinline__ s16x8 ldfrag(const void* base, size_t elem_off, int f32) {
    if (f32) {
        const float* f = (const float*)base + elem_off;
        const float4 a = *(const float4*)f;
        const float4 b = *(const float4*)(f + 4);
        return (s16x8){(short)f2bf(a.x), (short)f2bf(a.y), (short)f2bf(a.z), (short)f2bf(a.w),
                       (short)f2bf(b.x), (short)f2bf(b.y), (short)f2bf(b.z), (short)f2bf(b.w)};
    }
    return *(const s16x8*)((const u16*)base + elem_off);
}

// ---------------------------------------------------------------------------
// Kernel 0: dtype sniffer. x ~ N(0,1). As bf16, exponent fields live in
// ~[117,129]; wild (outside [102,144], nonzero) count ~0. As fp32 misread,
// even-index u16s are mantissa slices -> ~83% wild. Threshold 256/4096.
// Re-runs every launch (graph-safe, no statics).
// ---------------------------------------------------------------------------
__global__ __launch_bounds__(256) void sniff_kernel(const u16* __restrict__ x,
                                                    u32* __restrict__ flag) {
    __shared__ int s[256];
    const int tid = threadIdx.x;
    int w = 0;
    for (int i = tid; i < 4096; i += 256) {
        const u32 e = (x[i] >> 7) & 0xFFu;
        if (e != 0u && (e < 0x66u || e > 0x90u)) w++;
    }
    s[tid] = w;
    __syncthreads();
    for (int st = 128; st > 0; st >>= 1) {
        if (tid < st) s[tid] += s[tid + st];
        __syncthreads();
    }
    if (tid == 0) flag[0] = (s[0] > 256) ? 1u : 0u;   // 1 = fp32 inputs
}

// ---------------------------------------------------------------------------
// Kernel 1: spatial = relu( (adj @ x) @ W_gcn^T + rowsum(adj) * b_gcn )
// spatial is ALWAYS bf16 (internal format). Inputs read via flag.
// ---------------------------------------------------------------------------
__global__ __launch_bounds__(256) void gcn_kernel(
    const void* __restrict__ x, const void* __restrict__ adj,
    const void* __restrict__ Wg, const void* __restrict__ bg,
    u16* __restrict__ spatial, const u32* __restrict__ flagp)
{
    __shared__ float adjf[NNODE * NNODE];
    __shared__ float xf[NNODE * NF];
    __shared__ float tf[NNODE * NF];
    __shared__ float rs[NNODE];

    const int f32 = flagp ? (int)flagp[0] : 0;
    const int tid = threadIdx.x;
    const int h0  = (tid & 31) * 4;
    const int ng  = tid >> 5;

    float w[4][16], bgv[4];
#pragma unroll
    for (int j = 0; j < 4; j++) {
#pragma unroll
        for (int f = 0; f < NF; f++) w[j][f] = lds1(Wg, (size_t)(h0 + j) * NF + f, f32);
        bgv[j] = lds1(bg, h0 + j, f32);
    }

    for (int b = blockIdx.x; b < BATCH; b += gridDim.x) {
        for (int i = tid; i < NNODE * NNODE; i += 256)
            adjf[i] = lds1(adj, (size_t)b * NNODE * NNODE + i, f32);
        for (int i = tid; i < NNODE * NF; i += 256)
            xf[i] = lds1(x, (size_t)b * NNODE * NF + i, f32);
        __syncthreads();

        for (int i = tid; i < NNODE * NF + NNODE; i += 256) {
            if (i < NNODE * NF) {
                const int n = i >> 4, f = i & 15;
                float a = 0.f;
#pragma unroll
                for (int m = 0; m < NNODE; m++) a += adjf[n * NNODE + m] * xf[m * NF + f];
                tf[i] = a;
            } else {
                const int n = i - NNODE * NF;
                float a = 0.f;
#pragma unroll
                for (int m = 0; m < NNODE; m++) a += adjf[n * NNODE + m];
                rs[n] = a;
            }
        }
        __syncthreads();

        for (int n = ng; n < NNODE; n += 8) {
            const float4* t4 = (const float4*)&tf[n * NF];
            float acc[4];
#pragma unroll
            for (int j = 0; j < 4; j++) acc[j] = rs[n] * bgv[j];
#pragma unroll
            for (int q = 0; q < 4; q++) {
                const float4 tv = t4[q];
#pragma unroll
                for (int j = 0; j < 4; j++) {
                    acc[j] += tv.x * w[j][q * 4 + 0] + tv.y * w[j][q * 4 + 1]
                            + tv.z * w[j][q * 4 + 2] + tv.w * w[j][q * 4 + 3];
                }
            }
            u32 lo = (u32)f2bf(fmaxf(acc[0], 0.f)) | ((u32)f2bf(fmaxf(acc[1], 0.f)) << 16);
            u32 hi = (u32)f2bf(fmaxf(acc[2], 0.f)) | ((u32)f2bf(fmaxf(acc[3], 0.f)) << 16);
            u32* dst = (u32*)&spatial[((size_t)(b * NNODE + n)) * HID + h0];
            dst[0] = lo; dst[1] = hi;
        }
        __syncthreads();
    }
}

// ---------------------------------------------------------------------------
// Kernel 2: fused GRU gates via MFMA 16x16x32 bf16. Simplified (no prefetch)
// grid-stride loop; one barrier per tile makes the spatial-aliases-out
// fallback race-free (each 16-row block read+written only by its owner WG).
// Wave jt owns 16 gate-cols; 6 persistent 16x128 B-slices in 96 VGPRs.
// ---------------------------------------------------------------------------
__global__ __launch_bounds__(512, 2) void gru_kernel(
    const u16* __restrict__ spatial, const void* __restrict__ h_prev,
    const void* __restrict__ W_ih, const void* __restrict__ W_hh,
    const void* __restrict__ b_ih, const void* __restrict__ b_hh,
    void* __restrict__ out, const u32* __restrict__ flagp)
{
    const int f32  = flagp ? (int)flagp[0] : 0;
    const int lane = threadIdx.x & 63;
    const int jt   = threadIdx.x >> 6;   // 0..7
    const int n16  = lane & 15;
    const int quad = lane >> 4;
    const int c    = jt * 16 + n16;      // gate column 0..127
    const int kob  = quad * 8;

    s16x8 Bir[4], Biz[4], Bin[4], Bhr[4], Bhz[4], Bhn[4];
#pragma unroll
    for (int kt = 0; kt < 4; kt++) {
        const int ko = kt * 32 + kob;
        Bir[kt] = ldfrag(W_ih, (size_t)(c)       * HID + ko, f32);
        Biz[kt] = ldfrag(W_ih, (size_t)(128 + c) * HID + ko, f32);
        Bin[kt] = ldfrag(W_ih, (size_t)(256 + c) * HID + ko, f32);
        Bhr[kt] = ldfrag(W_hh, (size_t)(c)       * HID + ko, f32);
        Bhz[kt] = ldfrag(W_hh, (size_t)(128 + c) * HID + ko, f32);
        Bhn[kt] = ldfrag(W_hh, (size_t)(256 + c) * HID + ko, f32);
    }
    const float br   = lds1(b_ih, c, f32)       + lds1(b_hh, c, f32);
    const float bz   = lds1(b_ih, 128 + c, f32) + lds1(b_hh, 128 + c, f32);
    const float bin_ = lds1(b_ih, 256 + c, f32);
    const float bhn  = lds1(b_hh, 256 + c, f32);

    for (int rb = blockIdx.x; rb < MBLK; rb += gridDim.x) {
        const size_t ar = (size_t)(rb * 16 + n16) * HID + kob;
        s16x8 As[4], Ah[4];
#pragma unroll
        for (int kt = 0; kt < 4; kt++) {
            As[kt] = *(const s16x8*)&spatial[ar + kt * 32];
            Ah[kt] = ldfrag(h_prev, ar + kt * 32, f32);
        }

        f32x4 air = {0,0,0,0}, aiz = {0,0,0,0}, ain = {0,0,0,0};
        f32x4 ahr = {0,0,0,0}, ahz = {0,0,0,0}, ahn = {0,0,0,0};
#pragma unroll
        for (int kt = 0; kt < 4; kt++) {
            air = __builtin_amdgcn_mfma_f32_16x16x32_bf16(As[kt], Bir[kt], air, 0, 0, 0);
            ahr = __builtin_amdgcn_mfma_f32_16x16x32_bf16(Ah[kt], Bhr[kt], ahr, 0, 0, 0);
            aiz = __builtin_amdgcn_mfma_f32_16x16x32_bf16(As[kt], Biz[kt], aiz, 0, 0, 0);
            ahz = __builtin_amdgcn_mfma_f32_16x16x32_bf16(Ah[kt], Bhz[kt], ahz, 0, 0, 0);
            ain = __builtin_amdgcn_mfma_f32_16x16x32_bf16(As[kt], Bin[kt], ain, 0, 0, 0);
            ahn = __builtin_amdgcn_mfma_f32_16x16x32_bf16(Ah[kt], Bhn[kt], ahn, 0, 0, 0);
        }

        __syncthreads();  // all waves' spatial reads of rows rb complete before
                          // any wave writes those rows (out-alias fallback)

        const int row0 = rb * 16 + quad * 4;
#pragma unroll
        for (int reg = 0; reg < 4; reg++) {
            const size_t o = (size_t)(row0 + reg) * HID + c;
            const float r  = sigm(air[reg] + ahr[reg] + br);
            const float z  = sigm(aiz[reg] + ahz[reg] + bz);
            const float nn = tanh_fast(ain[reg] + bin_ + r * (ahn[reg] + bhn));
            const float hp = lds1(h_prev, o, f32);
            st1(out, o, f32, (1.0f - z) * nn + z * hp);
        }
    }
}

extern "C" void kernel_launch(void* const* d_in, const int* in_sizes, int n_in,
                              void* d_out, int out_size, void* d_ws, size_t ws_size,
                              hipStream_t stream) {
    const void* x      = d_in[0];
    const void* adj    = d_in[1];
    const void* h_prev = d_in[2];
    const void* W_gcn  = d_in[3];
    const void* b_gcn  = d_in[4];
    const void* W_ih   = d_in[5];
    const void* W_hh   = d_in[6];
    const void* b_ih   = d_in[7];
    const void* b_hh   = d_in[8];

    const size_t need = (size_t)MROWS * HID * sizeof(u16);  // 92 MB bf16 spatial
    u16* spatial;
    u32* flagp;
    if (ws_size >= need + 4) {
        spatial = (u16*)d_ws;
        flagp   = (u32*)((char*)d_ws + need);
    } else {
        spatial = (u16*)d_out;                      // race-free (see gru_kernel)
        flagp   = (ws_size >= 4) ? (u32*)d_ws : nullptr;
    }

    if (flagp) sniff_kernel<<<1, 256, 0, stream>>>((const u16*)x, flagp);
    gcn_kernel<<<4096, 256, 0, stream>>>(x, adj, W_gcn, b_gcn, spatial, flagp);
    gru_kernel<<<2048, 512, 0, stream>>>(spatial, h_prev, W_ih, W_hh, b_ih, b_hh,
                                         d_out, flagp);
}